// Round 9
// baseline (123.622 us; speedup 1.0000x reference)
//
#include <hip/hip_runtime.h>

// GCNCriticNet, round 9.
// deg==16 uniform => GCN agg == group mean (edge arrays dead).
// prep: f32 weights -> hi/lo bf16 16x16-MFMA B-frag tables in d_ws (coalesced).
// main: 256-thr blocks = 4 waves = 4 groups (1 group/wave, x = 32 acc VGPRs),
// 2048 blocks, __launch_bounds__(256,5) -> VGPR cap 102 (no spill, unlike
// R8's 85) -> 5 blocks/CU = 20 waves/CU, 4-wave barrier domain.
// emb: 16x16x32, B-frags straight from L2 tab (LDS stays 12.4 KB).
// layer matvec: block-batched, A = 4 means (+12 zero rows), wave owns 2
// N-tiles, kc0 B-frags prefetched before the mean phase.

#define N_GRAPHS 8192
#define BLOCK    256
#define GPB      4
#define NBLOCKS  (N_GRAPHS / GPB)   // 2048

typedef __attribute__((ext_vector_type(8))) short short8;    // 8 bf16
typedef __attribute__((ext_vector_type(4))) float floatx4;   // 16x16 C/D

#define MFMA16(a, b, c) __builtin_amdgcn_mfma_f32_16x16x32_bf16((a), (b), (c), 0, 0, 0)

// ws frag-table layout (short8 units), all 16x16x32 B layout:
//   emb: hi f = kc*512 + nt*64 + L in [0,1024); lo at f+1024
//   gcn l: hi at 2048 + l*4096 + kc*512 + nt*64 + L; lo at +2048
#define EMB_LO   1024
#define GCN_BASE 2048
#define GCN_LO   2048

union fragu { unsigned int u[4]; short8 s8; };

__device__ __forceinline__ unsigned fbits(float x) {
  union { float f; unsigned u; } v; v.f = x; return v.u;
}
__device__ __forceinline__ float bitsf(unsigned u) {
  union { float f; unsigned u; } v; v.u = u; return v.f;
}
__device__ __forceinline__ void bsplit(float x, short& hi, short& lo) {
  unsigned hb = fbits(x) & 0xFFFF0000u;
  hi = (short)(hb >> 16);
  lo = (short)(fbits(x - bitsf(hb)) >> 16);
}
// dst halfwords: lo16 = hi16(b_even), hi16 = hi16(b_odd)
__device__ __forceinline__ unsigned hpack(unsigned b_odd, unsigned b_even) {
  return __builtin_amdgcn_perm(b_odd, b_even, 0x07060302u);
}
__device__ __forceinline__ void mk_frags(float4 a, float4 b, short8& hi, short8& lo) {
  fragu H, L;
  H.u[0] = hpack(fbits(a.y), fbits(a.x));
  H.u[1] = hpack(fbits(a.w), fbits(a.z));
  H.u[2] = hpack(fbits(b.y), fbits(b.x));
  H.u[3] = hpack(fbits(b.w), fbits(b.z));
  float l0 = a.x - bitsf(fbits(a.x) & 0xFFFF0000u);
  float l1 = a.y - bitsf(fbits(a.y) & 0xFFFF0000u);
  float l2 = a.z - bitsf(fbits(a.z) & 0xFFFF0000u);
  float l3 = a.w - bitsf(fbits(a.w) & 0xFFFF0000u);
  float l4 = b.x - bitsf(fbits(b.x) & 0xFFFF0000u);
  float l5 = b.y - bitsf(fbits(b.y) & 0xFFFF0000u);
  float l6 = b.z - bitsf(fbits(b.z) & 0xFFFF0000u);
  float l7 = b.w - bitsf(fbits(b.w) & 0xFFFF0000u);
  L.u[0] = hpack(fbits(l1), fbits(l0));
  L.u[1] = hpack(fbits(l3), fbits(l2));
  L.u[2] = hpack(fbits(l5), fbits(l4));
  L.u[3] = hpack(fbits(l7), fbits(l6));
  hi = H.s8; lo = L.s8;
}
__device__ __forceinline__ float fast_tanh(float z) {
  float e = __expf(2.0f * z);
  return 1.0f - __fdividef(2.0f, e + 1.0f);
}

// ---- prep: one frag per thread, j-loop inside => lane dim = frag lane ----
__global__ __launch_bounds__(256) void gcn_prep(
    const float* __restrict__ w_emb, const float* __restrict__ w_gcn,
    unsigned short* __restrict__ wsS)
{
  int f = blockIdx.x * 256 + threadIdx.x;     // frag id 0..5119
  if (f >= 5120) return;
  const float* src;
  int hi_f, lo_f;
  if (f < 1024) {                             // emb, 16x16 frags
    int kc = f >> 9, nt = (f >> 6) & 7, L = f & 63;
    int k0 = kc * 32 + (L >> 4) * 8, n = nt * 16 + (L & 15);
    src = w_emb + k0 * 128 + n;
    hi_f = f; lo_f = f + EMB_LO;
  } else {
    int f2 = f - 1024;
    int l = f2 >> 11, r = f2 & 2047;
    int kc = r >> 9, nt = (r >> 6) & 7, L = r & 63;
    int k0 = kc * 32 + (L >> 4) * 8, n = nt * 16 + (L & 15);
    src = w_gcn + l * 16384 + k0 * 128 + n;
    hi_f = GCN_BASE + l * 4096 + r; lo_f = hi_f + GCN_LO;
  }
  #pragma unroll
  for (int j = 0; j < 8; ++j) {
    short h, l_;
    bsplit(src[j * 128], h, l_);
    wsS[hi_f * 8 + j] = (unsigned short)h;
    wsS[lo_f * 8 + j] = (unsigned short)l_;
  }
}

__global__ __launch_bounds__(BLOCK, 5) void gcn_main(
    const float* __restrict__ obs,
    const float* __restrict__ b_emb,
    const float* __restrict__ b_gcn,
    const float* __restrict__ w_fc1,
    const float* __restrict__ b_fc1,
    const short8* __restrict__ tab,
    float* __restrict__ out)
{
  // A-frag table: [hl][kc4][row16][40 shorts]; rows 0-3 real means, 4-15 zero
  __shared__ short sA[2 * 4 * 16 * 40];    // 10.25 KB
  __shared__ float sH[4][132];             // 2.1 KB matvec outs [group][col]

  const int tid = threadIdx.x;
  const int w   = tid >> 6;                // wave = group-in-block (0..3)
  const int L   = tid & 63;
  const int c16 = L & 15;
  const int q   = L >> 4;
  const int kh  = L >> 5;                  // hi/lo writer half
  const int group = blockIdx.x * GPB + w;

  // ---- obs loads first; A[m=c16 (node)][k = kc*32 + q*8 + j] ----
  const float* op = obs + (group * 16 + c16) * 64 + q * 8;
  float4 o00 = *(const float4*)(op);
  float4 o01 = *(const float4*)(op + 4);
  float4 o10 = *(const float4*)(op + 32);
  float4 o11 = *(const float4*)(op + 36);

  // ---- zero sA rows 4-15 (disjoint from mean rows 0-3 -> no extra barrier)
  {
    unsigned int* za = (unsigned int*)sA;  // 1920 dwords live in rows 4-15
    #pragma unroll
    for (int z = 0; z < 8; ++z) {
      int i = z * BLOCK + tid;
      if (i < 1920) {
        int reg = i / 240, rm = i - reg * 240;
        int r12 = rm / 20, cw = rm - r12 * 20;
        za[reg * 320 + (r12 + 4) * 20 + cw] = 0;
      }
    }
  }

  floatx4 x[8];
  #pragma unroll
  for (int nt = 0; nt < 8; ++nt) {
    float b = b_emb[nt * 16 + c16];
    x[nt] = (floatx4){b, b, b, b};
  }

  // ---- embedding: x = obs @ w_emb + b_emb; 8 N-tiles, 2 kc chunks ----
  #pragma unroll
  for (int kc = 0; kc < 2; ++kc) {
    short8 ah, al;
    mk_frags(kc ? o10 : o00, kc ? o11 : o01, ah, al);
    #pragma unroll
    for (int nt = 0; nt < 8; ++nt) {
      int idx = kc * 512 + nt * 64 + L;
      short8 bh = tab[idx];
      short8 bl = tab[idx + EMB_LO];
      x[nt] = MFMA16(ah, bh, x[nt]);
      x[nt] = MFMA16(al, bh, x[nt]);
      x[nt] = MFMA16(ah, bl, x[nt]);
    }
  }

  // ---- GCN layers: x = tanh((mean_g x) @ W_l + b_l + x) ----
  #pragma unroll 1
  for (int l = 0; l < 2; ++l) {
    // wave w owns N-tiles {2w, 2w+1}; prefetch kc0 frags before mean phase
    const short8* tb0 = tab + GCN_BASE + l * 4096 + (2 * w) * 64 + L;
    const short8* tb1 = tb0 + 64;
    short8 bh0 = tb0[0], bl0 = tb0[GCN_LO];
    short8 bh1 = tb1[0], bl1 = tb1[GCN_LO];

    // mean of my group -> cooperative bf16 A-table row w.
    // col k = nt*16+c16 -> (kc = nt>>1, q' = (nt&1)*2 + (c16>>3), j = c16&7);
    // writers: even c16, even q; kh selects hi/lo table.
    #pragma unroll
    for (int nt = 0; nt < 8; ++nt) {
      float s = x[nt][0] + x[nt][1] + x[nt][2] + x[nt][3];
      s += __shfl_xor(s, 16);
      s += __shfl_xor(s, 32);
      float v = s * 0.0625f;
      unsigned hb = fbits(v) & 0xFFFF0000u;
      unsigned vb = (kh == 0) ? hb : fbits(v - bitsf(hb));
      unsigned nb = (unsigned)__shfl_xor((int)vb, 1);
      if (((c16 & 1) | (q & 1)) == 0) {
        unsigned pw = hpack(nb, vb);
        int kc = nt >> 1, qp = ((nt & 1) << 1) | (c16 >> 3), j = c16 & 7;
        int hw = kh * 2560 + kc * 640 + w * 40 + qp * 8 + j;
        *(unsigned int*)&sA[hw] = pw;
      }
    }
    __syncthreads();

    // batched matvec: A = 4 means (+12 zero rows); rolling B prefetch
    floatx4 h0 = {0.f, 0.f, 0.f, 0.f};
    floatx4 h1 = {0.f, 0.f, 0.f, 0.f};
    #pragma unroll
    for (int kc = 0; kc < 4; ++kc) {
      short8 ah = *(const short8*)&sA[kc * 640 + c16 * 40 + q * 8];
      short8 al = *(const short8*)&sA[2560 + kc * 640 + c16 * 40 + q * 8];
      short8 cbh0 = bh0, cbl0 = bl0, cbh1 = bh1, cbl1 = bl1;
      if (kc < 3) {
        bh0 = tb0[(kc + 1) * 512]; bl0 = tb0[(kc + 1) * 512 + GCN_LO];
        bh1 = tb1[(kc + 1) * 512]; bl1 = tb1[(kc + 1) * 512 + GCN_LO];
      }
      h0 = MFMA16(ah, cbh0, h0); h1 = MFMA16(ah, cbh1, h1);
      h0 = MFMA16(al, cbh0, h0); h1 = MFMA16(al, cbh1, h1);
      h0 = MFMA16(ah, cbl0, h0); h1 = MFMA16(ah, cbl1, h1);
    }
    // h rows 0-3 = the 4 groups (q==0 lanes); fold per-col bias at write
    if (q == 0) {
      float bg0 = b_gcn[l * 128 + (2 * w) * 16 + c16];
      float bg1 = b_gcn[l * 128 + (2 * w + 1) * 16 + c16];
      #pragma unroll
      for (int r = 0; r < 4; ++r) {
        sH[r][(2 * w) * 16 + c16]     = h0[r] + bg0;
        sH[r][(2 * w + 1) * 16 + c16] = h1[r] + bg1;
      }
    }
    __syncthreads();

    // residual + tanh: z per col from my group's sH row
    #pragma unroll
    for (int nt = 0; nt < 8; ++nt) {
      float z = sH[w][nt * 16 + c16];
      x[nt][0] = fast_tanh(x[nt][0] + z);
      x[nt][1] = fast_tanh(x[nt][1] + z);
      x[nt][2] = fast_tanh(x[nt][2] + z);
      x[nt][3] = fast_tanh(x[nt][3] + z);
    }
  }

  // ---- value head: out[g] = (1/16) sum_{node,col} x * w_fc1[col] + b ----
  float v = 0.f;
  #pragma unroll
  for (int nt = 0; nt < 8; ++nt) {
    float wf = w_fc1[nt * 16 + c16];
    v = fmaf(x[nt][0] + x[nt][1] + x[nt][2] + x[nt][3], wf, v);
  }
  #pragma unroll
  for (int d = 32; d >= 1; d >>= 1) v += __shfl_xor(v, d);
  if (L == 0) out[group] = v * 0.0625f + b_fc1[0];
}

extern "C" void kernel_launch(void* const* d_in, const int* in_sizes, int n_in,
                              void* d_out, int out_size, void* d_ws, size_t ws_size,
                              hipStream_t stream) {
  const float* obs    = (const float*)d_in[0];   // [131072, 64]
  const float* w_emb  = (const float*)d_in[1];   // [64, 128]
  const float* b_emb  = (const float*)d_in[2];   // [128]
  const float* w_gcn  = (const float*)d_in[3];   // [2, 128, 128]
  const float* b_gcn  = (const float*)d_in[4];   // [2, 128]
  const float* w_fc1  = (const float*)d_in[5];   // [128, 1]
  const float* b_fc1  = (const float*)d_in[6];   // [1]
  // d_in[7], d_in[8]: edge_src/edge_dst — redundant (deg==16 uniform)
  float* out = (float*)d_out;                    // [8192]

  gcn_prep<<<20, 256, 0, stream>>>(w_emb, w_gcn, (unsigned short*)d_ws);
  gcn_main<<<NBLOCKS, BLOCK, 0, stream>>>(obs, b_emb, b_gcn, w_fc1, b_fc1,
                                          (const short8*)d_ws, out);
}

// Round 10
// 120.114 us; speedup vs baseline: 1.0292x; 1.0292x over previous
//
#include <hip/hip_runtime.h>

// GCNCriticNet, round 10 = R6 (best, ~41us main) + emb B-frag rolling
// prefetch + launch_bounds(256,3) for in-flight-load headroom.
// deg==16 uniform => GCN agg == group mean (edge arrays dead).
// prep: f32 weights -> hi/lo bf16 MFMA B-frag tables in d_ws (once/call).
// main: 256 thr = 4 waves = 8 groups (2/wave); emb 32x32x16, B-frags from
// L2 tab with depth-1 rolling prefetch; layer matvec block-batched via
// cooperative bf16 A-table (8 mean rows + 8 zero rows).
// 3-term hi/lo split (hh+lh+hl) ~ f32 accuracy.

#define N_GRAPHS 8192
#define BLOCK    256
#define NBLOCKS  (N_GRAPHS / 8)   // 1024 blocks, 8 groups each

typedef __attribute__((ext_vector_type(8)))  short short8;    // 8 bf16
typedef __attribute__((ext_vector_type(4)))  float floatx4;   // 16x16 C/D
typedef __attribute__((ext_vector_type(16))) float floatx16;  // 32x32 C/D

#define MFMA16(a, b, c) __builtin_amdgcn_mfma_f32_16x16x32_bf16((a), (b), (c), 0, 0, 0)
#define MFMA32(a, b, c) __builtin_amdgcn_mfma_f32_32x32x16_bf16((a), (b), (c), 0, 0, 0)

// ws frag-table layout (short8 units):
//   emb hi [0,1024), emb lo [1024,2048)
//   gcn l: hi at 2048 + l*4096 + kc*512 + nt*64 + lane; lo at +2048
#define EMB_LO   1024
#define GCN_BASE 2048
#define GCN_LO   2048

union fragu { unsigned int u[4]; short8 s8; };

__device__ __forceinline__ unsigned fbits(float x) {
  union { float f; unsigned u; } v; v.f = x; return v.u;
}
__device__ __forceinline__ float bitsf(unsigned u) {
  union { float f; unsigned u; } v; v.u = u; return v.f;
}
__device__ __forceinline__ void bsplit(float x, short& hi, short& lo) {
  unsigned hb = fbits(x) & 0xFFFF0000u;
  hi = (short)(hb >> 16);
  lo = (short)(fbits(x - bitsf(hb)) >> 16);
}
__device__ __forceinline__ unsigned hpack(unsigned b_odd, unsigned b_even) {
  return __builtin_amdgcn_perm(b_odd, b_even, 0x07060302u);
}
__device__ __forceinline__ void mk_frags(float4 a, float4 b, short8& hi, short8& lo) {
  fragu H, L;
  H.u[0] = hpack(fbits(a.y), fbits(a.x));
  H.u[1] = hpack(fbits(a.w), fbits(a.z));
  H.u[2] = hpack(fbits(b.y), fbits(b.x));
  H.u[3] = hpack(fbits(b.w), fbits(b.z));
  float l0 = a.x - bitsf(fbits(a.x) & 0xFFFF0000u);
  float l1 = a.y - bitsf(fbits(a.y) & 0xFFFF0000u);
  float l2 = a.z - bitsf(fbits(a.z) & 0xFFFF0000u);
  float l3 = a.w - bitsf(fbits(a.w) & 0xFFFF0000u);
  float l4 = b.x - bitsf(fbits(b.x) & 0xFFFF0000u);
  float l5 = b.y - bitsf(fbits(b.y) & 0xFFFF0000u);
  float l6 = b.z - bitsf(fbits(b.z) & 0xFFFF0000u);
  float l7 = b.w - bitsf(fbits(b.w) & 0xFFFF0000u);
  L.u[0] = hpack(fbits(l1), fbits(l0));
  L.u[1] = hpack(fbits(l3), fbits(l2));
  L.u[2] = hpack(fbits(l5), fbits(l4));
  L.u[3] = hpack(fbits(l7), fbits(l6));
  hi = H.s8; lo = L.s8;
}
__device__ __forceinline__ float fast_tanh(float z) {
  float e = __expf(2.0f * z);
  return 1.0f - __fdividef(2.0f, e + 1.0f);
}

// ---- prep: one (frag,j) element per thread; 160 blocks x 256 ----
__global__ __launch_bounds__(256) void gcn_prep(
    const float* __restrict__ w_emb, const float* __restrict__ w_gcn,
    unsigned short* __restrict__ wsS)
{
  int idx = blockIdx.x * 256 + threadIdx.x;
  if (idx >= 40960) return;
  int f = idx >> 3, j = idx & 7;
  const float* src;
  int hi_f, lo_f;
  if (f < 1024) {                       // emb: 32x32x16 B layout
    int ks = f >> 8, t = (f >> 6) & 3, L = f & 63;
    int k0 = ks * 16 + (L >> 5) * 8;    // B[k][n]: k=(lane>>5)*8+j
    int n  = t * 32 + (L & 31);
    src = w_emb + k0 * 128 + n;
    hi_f = f; lo_f = f + EMB_LO;
  } else {                              // gcn: 16x16x32 B layout
    int f2 = f - 1024;
    int l = f2 >> 11, r = f2 & 2047;
    int kc = r >> 9, nt = (r >> 6) & 7, L = r & 63;
    int k0 = kc * 32 + (L >> 4) * 8;    // B[k][n]: k=(lane>>4)*8+j
    int n  = nt * 16 + (L & 15);
    src = w_gcn + l * 16384 + k0 * 128 + n;
    hi_f = GCN_BASE + l * 4096 + r; lo_f = hi_f + GCN_LO;
  }
  short h, l_;
  bsplit(src[j * 128], h, l_);
  wsS[hi_f * 8 + j] = (unsigned short)h;
  wsS[lo_f * 8 + j] = (unsigned short)l_;
}

__global__ __launch_bounds__(BLOCK, 3) void gcn_main(
    const float* __restrict__ obs,
    const float* __restrict__ b_emb,
    const float* __restrict__ b_gcn,
    const float* __restrict__ w_fc1,
    const float* __restrict__ b_fc1,
    const short8* __restrict__ tab,
    float* __restrict__ out)
{
  // A-frag table: [hl][kc4][row16][40 shorts] (row stride 80B, 16B-aligned)
  __shared__ short sA[2 * 4 * 16 * 40];   // 10.25 KB
  __shared__ float sH[8][129];            // matvec outputs per group

  const int tid = threadIdx.x;
  const int w   = tid >> 6;
  const int L   = tid & 63;
  const int m32 = L & 31;
  const int kh  = L >> 5;
  const int c16 = L & 15;
  const int q   = L >> 4;
  const int gw  = blockIdx.x * 8 + 2 * w;   // wave's first group

  // zero A-table rows 8-15 once (disjoint from rows 0-7 the layers write)
  {
    unsigned int* za = (unsigned int*)sA;   // 1280 dwords in rows 8-15
    #pragma unroll
    for (int jz = 0; jz < 5; ++jz) {
      int i   = tid + 256 * jz;
      int tb_ = i / 160;                    // [hl][kc] region 0..7
      int rm  = i - tb_ * 160;
      int rr  = rm / 20, cw = rm - rr * 20;
      za[tb_ * 320 + (rr + 8) * 20 + cw] = 0;
    }
  }

  // ---- embedding: x = obs @ w_emb + b_emb; 4 N-tiles of 32 cols ----
  // A[m=L&31][k = s*16 + kh*8 + j]; rolling obs prefetch (distance 2)
  const float* op = obs + (gw * 16 + m32) * 64 + kh * 8;
  float4 oa0 = *(const float4*)(op);
  float4 oa1 = *(const float4*)(op + 4);
  float4 ob0 = *(const float4*)(op + 16);
  float4 ob1 = *(const float4*)(op + 20);

  // rolling depth-1 prefetch of emb B-frags (8 bufs = 32 VGPR): the loads
  // for step s+1 are in flight across step s's mk_frags + 12 MFMA32s.
  short8 pbh[4], pbl[4];
  #pragma unroll
  for (int t = 0; t < 4; ++t) {
    pbh[t] = tab[t * 64 + L];
    pbl[t] = tab[t * 64 + L + EMB_LO];
  }

  floatx16 x[4];
  #pragma unroll
  for (int t = 0; t < 4; ++t) {
    float b = b_emb[t * 32 + m32];
    #pragma unroll
    for (int r = 0; r < 16; ++r) x[t][r] = b;
  }

  #pragma unroll
  for (int s = 0; s < 4; ++s) {
    short8 ah, al;
    mk_frags(oa0, oa1, ah, al);
    oa0 = ob0; oa1 = ob1;
    if (s < 2) {
      ob0 = *(const float4*)(op + (s + 2) * 16);
      ob1 = *(const float4*)(op + (s + 2) * 16 + 4);
    }
    short8 cbh[4], cbl[4];
    #pragma unroll
    for (int t = 0; t < 4; ++t) { cbh[t] = pbh[t]; cbl[t] = pbl[t]; }
    if (s < 3) {
      #pragma unroll
      for (int t = 0; t < 4; ++t) {
        pbh[t] = tab[((s + 1) * 4 + t) * 64 + L];
        pbl[t] = tab[((s + 1) * 4 + t) * 64 + L + EMB_LO];
      }
    }
    #pragma unroll
    for (int t = 0; t < 4; ++t) {
      x[t] = MFMA32(ah, cbh[t], x[t]);
      x[t] = MFMA32(al, cbh[t], x[t]);
      x[t] = MFMA32(ah, cbl[t], x[t]);
    }
  }

  // ---- GCN layers: x = tanh((mean_g x) @ W_l + b_l + x) ----
  #pragma unroll 1
  for (int l = 0; l < 2; ++l) {
    const short8* t0 = tab + GCN_BASE + l * 4096 + (2 * w) * 64 + L;
    const short8* t1 = t0 + 64;
    // kc=0 B-frags prefetch (hides L2 latency under mean build + barrier)
    short8 cbh0 = t0[0], cbh1 = t1[0];
    short8 cbl0 = t0[GCN_LO], cbl1 = t1[GCN_LO];

    // means -> packed bf16 hi/lo A-table rows 2w, 2w+1 (cooperative):
    // lanes kh=0 write hi half, kh=1 lo half; even cols pack lane pairs.
    #pragma unroll
    for (int t = 0; t < 4; ++t) {
      float s0 = x[t][0], s1 = x[t][8];
      #pragma unroll
      for (int r = 1; r < 8; ++r) { s0 += x[t][r]; s1 += x[t][r + 8]; }
      s0 += __shfl_xor(s0, 32);
      s1 += __shfl_xor(s1, 32);
      s0 *= 0.0625f; s1 *= 0.0625f;
      #pragma unroll
      for (int rr = 0; rr < 2; ++rr) {
        float v = rr ? s1 : s0;
        unsigned hb = fbits(v) & 0xFFFF0000u;
        unsigned vb = (kh == 0) ? hb : fbits(v - bitsf(hb));
        unsigned nb = (unsigned)__shfl_xor((int)vb, 1);
        unsigned pw = hpack(nb, vb);
        if ((m32 & 1) == 0) {
          int si = kh * 2560 + t * 640 + (2 * w + rr) * 40 + m32;
          *(unsigned int*)&sA[si] = pw;
        }
      }
    }
    __syncthreads();

    // block-batched matvec: A = 8 means (+8 zero rows); wave w -> 2 N-tiles
    floatx4 h0 = {0.f, 0.f, 0.f, 0.f};
    floatx4 h1 = {0.f, 0.f, 0.f, 0.f};
    #pragma unroll
    for (int kc = 0; kc < 4; ++kc) {
      short8 ah = *(const short8*)&sA[kc * 640 + c16 * 40 + q * 8];
      short8 al = *(const short8*)&sA[2560 + kc * 640 + c16 * 40 + q * 8];
      short8 nbh0, nbh1, nbl0, nbl1;
      if (kc < 3) {
        nbh0 = t0[(kc + 1) * 512];
        nbh1 = t1[(kc + 1) * 512];
        nbl0 = t0[(kc + 1) * 512 + GCN_LO];
        nbl1 = t1[(kc + 1) * 512 + GCN_LO];
      }
      h0 = MFMA16(ah, cbh0, h0); h1 = MFMA16(ah, cbh1, h1);
      h0 = MFMA16(al, cbh0, h0); h1 = MFMA16(al, cbh1, h1);
      h0 = MFMA16(ah, cbl0, h0); h1 = MFMA16(ah, cbl1, h1);
      cbh0 = nbh0; cbh1 = nbh1; cbl0 = nbl0; cbl1 = nbl1;
    }
    // scatter rows 0-7 (the 8 groups) to sH at this wave's 32 cols
    if (q < 2) {
      #pragma unroll
      for (int r = 0; r < 4; ++r) {
        sH[q * 4 + r][(2 * w) * 16 + c16]     = h0[r];
        sH[q * 4 + r][(2 * w + 1) * 16 + c16] = h1[r];
      }
    }
    __syncthreads();

    // residual + bias + tanh (x stays in 32x32 C layout)
    #pragma unroll
    for (int t = 0; t < 4; ++t) {
      float b  = b_gcn[l * 128 + t * 32 + m32];
      float zA = sH[2 * w][t * 32 + m32] + b;
      float zB = sH[2 * w + 1][t * 32 + m32] + b;
      #pragma unroll
      for (int r = 0; r < 8; ++r) {
        x[t][r]     = fast_tanh(x[t][r] + zA);
        x[t][r + 8] = fast_tanh(x[t][r + 8] + zB);
      }
    }
  }

  // ---- value head: out[g] = (1/16) sum_{node,col} x * w_fc1[col] + b ----
  float vA = 0.f, vB = 0.f;
  #pragma unroll
  for (int t = 0; t < 4; ++t) {
    float wf = w_fc1[t * 32 + m32];
    float sA_ = 0.f, sB_ = 0.f;
    #pragma unroll
    for (int r = 0; r < 8; ++r) { sA_ += x[t][r]; sB_ += x[t][r + 8]; }
    vA = fmaf(sA_, wf, vA);
    vB = fmaf(sB_, wf, vB);
  }
  #pragma unroll
  for (int d = 32; d >= 1; d >>= 1) {
    vA += __shfl_xor(vA, d);
    vB += __shfl_xor(vB, d);
  }
  if (L == 0) {
    float bf = b_fc1[0];
    out[gw]     = vA * 0.0625f + bf;
    out[gw + 1] = vB * 0.0625f + bf;
  }
}

extern "C" void kernel_launch(void* const* d_in, const int* in_sizes, int n_in,
                              void* d_out, int out_size, void* d_ws, size_t ws_size,
                              hipStream_t stream) {
  const float* obs    = (const float*)d_in[0];   // [131072, 64]
  const float* w_emb  = (const float*)d_in[1];   // [64, 128]
  const float* b_emb  = (const float*)d_in[2];   // [128]
  const float* w_gcn  = (const float*)d_in[3];   // [2, 128, 128]
  const float* b_gcn  = (const float*)d_in[4];   // [2, 128]
  const float* w_fc1  = (const float*)d_in[5];   // [128, 1]
  const float* b_fc1  = (const float*)d_in[6];   // [1]
  // d_in[7], d_in[8]: edge_src/edge_dst — redundant (deg==16 uniform)
  float* out = (float*)d_out;                    // [8192]

  gcn_prep<<<160, 256, 0, stream>>>(w_emb, w_gcn, (unsigned short*)d_ws);
  gcn_main<<<NBLOCKS, BLOCK, 0, stream>>>(obs, b_emb, b_gcn, w_fc1, b_fc1,
                                          (const short8*)d_ws, out);
}